// Round 15
// baseline (120.878 us; speedup 1.0000x reference)
//
#include <hip/hip_runtime.h>
#include <hip/hip_bf16.h>

#define NUM_HEADS 16
#define HEAD_DIM 64
#define DMODEL 1024
#define SEQ 2048
#define BATCH 2
#define MROWS (BATCH*SEQ)

typedef __bf16 bf16;
typedef __bf16 bf16x4 __attribute__((ext_vector_type(4)));
typedef __bf16 bf16x8 __attribute__((ext_vector_type(8)));
typedef float f32x4 __attribute__((ext_vector_type(4)));

#define MFMA16(a, b, c) __builtin_amdgcn_mfma_f32_16x16x32_bf16((a), (b), (c), 0, 0, 0)

// 0.125 * log2(e): folded into Q so QK^T logits land in exp2 domain
#define QSCALE 0.1803368801111444f

__device__ __forceinline__ float fast_exp2(float x) {
    float r;
    asm("v_exp_f32 %0, %1" : "=v"(r) : "v"(x));
    return r;
}

__device__ __forceinline__ void gld16(const void* g, void* l) {
    __builtin_amdgcn_global_load_lds(
        (const __attribute__((address_space(1))) void*)g,
        (__attribute__((address_space(3))) void*)l, 16, 0, 0);
}

// ---------------- merged conversion kernel (single launch) ----------------
__global__ __launch_bounds__(256) void cvt_all(const float* __restrict__ x,
                                               const float* __restrict__ w0, const float* __restrict__ w1,
                                               const float* __restrict__ w2, const float* __restrict__ w3,
                                               bf16* __restrict__ xb,
                                               bf16* __restrict__ o0, bf16* __restrict__ o1,
                                               bf16* __restrict__ o2, bf16* __restrict__ o3) {
    __shared__ bf16 tile[64][65];
    int id = blockIdx.x;
    if (id < 4096) {
        int i = id * 256 + threadIdx.x;          // i < 1048576 = MROWS*DMODEL/4
        float4 v = *(const float4*)(x + (size_t)i * 4);
        bf16x4 o = { (bf16)v.x, (bf16)v.y, (bf16)v.z, (bf16)v.w };
        *(bf16x4*)(xb + (size_t)i * 4) = o;
        return;
    }
    id -= 4096;
    int z = id >> 8, r = id & 255;
    int by = r >> 4, bx = r & 15;
    const float* w = z == 0 ? w0 : z == 1 ? w1 : z == 2 ? w2 : w3;
    bf16* o = z == 0 ? o0 : z == 1 ? o1 : z == 2 ? o2 : o3;
    int k0 = by * 64, n0 = bx * 64;
    int tc = threadIdx.x & 63;
    int tr0 = threadIdx.x >> 6;
#pragma unroll
    for (int i = 0; i < 16; i++) {
        int rr = tr0 + i * 4;
        tile[rr][tc] = (bf16)w[(size_t)(k0 + rr) * DMODEL + n0 + tc];
    }
    __syncthreads();
#pragma unroll
    for (int i = 0; i < 16; i++) {
        int rr = tr0 + i * 4;
        o[(size_t)(n0 + rr) * DMODEL + k0 + tc] = tile[tc][rr];
    }
}

// ---------------- GEMM core: C[128][64] tile = A[m][k] * Bt[n][k]^T ----------------
// R12-proven 2-phase loop (BK=32, single buffer, linear LDS, compiler-scheduled)
// with BN halved 128->64: qkv grid 768->1536 blocks (3->6 blocks/CU), outp
// 256->512 (1->2 blocks/CU). Rationale: the per-K-step drain stall was exposed
// by too few independent barrier groups per CU (same diagnosis as attn R7->R8);
// LDS/block drops to 12KB so 6 blocks co-reside. Per-CU LDS traffic at 6 blocks
// (~844 cyc/K-step) stays under the measured stall-bound period (~1160).
// Falsified: R9 triple-buffer+vmcnt (m132/m141), R13 BK=64+swizzle (T2 gate).

#define BM 128
#define BN 64
#define BK 32

__device__ __forceinline__ void gemm_core(const bf16* __restrict__ A, const bf16* __restrict__ Bt,
                                          int m0, int n0, int Kdim,
                                          bf16* As, bf16* Bs, f32x4 acc[4][2]) {
    int t = threadIdx.x;
    int lane = t & 63;
    int wave = t >> 6;
    int wm = (wave >> 1) * 64;     // m-half
    int wn = (wave & 1) * 32;      // n-half (32 wide)
#pragma unroll
    for (int mf = 0; mf < 4; mf++)
#pragma unroll
        for (int nf = 0; nf < 2; nf++) acc[mf][nf] = (f32x4){0.f, 0.f, 0.f, 0.f};

    int arow = lane & 15, kg = lane >> 4;

    for (int k0 = 0; k0 < Kdim; k0 += BK) {
        __syncthreads();
        // A 128x32: 512 chunks, 2/thread. B 64x32: 256 chunks, 1/thread.
#pragma unroll
        for (int it = 0; it < 2; it++) {
            int chunk = it * 256 + t;
            int rr = chunk >> 2, cc = chunk & 3;
            gld16(A + (size_t)(m0 + rr) * Kdim + k0 + cc * 8, As + chunk * 8);
        }
        {
            int rr = t >> 2, cc = t & 3;
            gld16(Bt + (size_t)(n0 + rr) * Kdim + k0 + cc * 8, Bs + t * 8);
        }
        __syncthreads();
        bf16x8 af[4], bfr[2];
#pragma unroll
        for (int mf = 0; mf < 4; mf++)
            af[mf] = *(const bf16x8*)(As + (wm + mf * 16 + arow) * BK + kg * 8);
#pragma unroll
        for (int nf = 0; nf < 2; nf++)
            bfr[nf] = *(const bf16x8*)(Bs + (wn + nf * 16 + arow) * BK + kg * 8);
#pragma unroll
        for (int mf = 0; mf < 4; mf++)
#pragma unroll
            for (int nf = 0; nf < 2; nf++)
                acc[mf][nf] = MFMA16(af[mf], bfr[nf], acc[mf][nf]);
    }
}

// z=0 -> Q head-major [B][H][S][D], pre-scaled by QSCALE; z=1 -> K head-major; z=2 -> V [B][H][D][S]
// grid (16,32,3), x-fastest: each CU sees the same A-panel across its blocks.
__global__ __launch_bounds__(256) void gemm_qkv(const bf16* __restrict__ xb,
                                                const bf16* __restrict__ wqT, const bf16* __restrict__ wkT,
                                                const bf16* __restrict__ wvT,
                                                bf16* __restrict__ Qh, bf16* __restrict__ Kh,
                                                bf16* __restrict__ Vt) {
    __shared__ __attribute__((aligned(16))) bf16 As[BM * BK];
    __shared__ __attribute__((aligned(16))) bf16 Bs[BN * BK];
    int z = blockIdx.z;
    const bf16* Bt = z == 0 ? wqT : z == 1 ? wkT : wvT;
    int m0 = blockIdx.y * BM, n0 = blockIdx.x * BN;
    f32x4 acc[4][2];
    gemm_core(xb, Bt, m0, n0, DMODEL, As, Bs, acc);

    int lane = threadIdx.x & 63, wave = threadIdx.x >> 6;
    int wm = (wave >> 1) * 64, wn = (wave & 1) * 32;
    int col0 = n0 + wn + (lane & 15);
    int row0 = m0 + wm + (lane >> 4) * 4;
    if (z < 2) {
        bf16* O = z == 0 ? Qh : Kh;
        float scl = z == 0 ? QSCALE : 1.0f;
#pragma unroll
        for (int mf = 0; mf < 4; mf++)
#pragma unroll
            for (int nf = 0; nf < 2; nf++) {
                int n = col0 + nf * 16;
                int mb = row0 + mf * 16;
                int hh = n >> 6, d = n & 63;
#pragma unroll
                for (int i2 = 0; i2 < 4; i2++) {
                    int m = mb + i2;
                    int bb = m >> 11, s = m & 2047;
                    O[(((size_t)bb * NUM_HEADS + hh) * SEQ + s) * HEAD_DIM + d] =
                        (bf16)(acc[mf][nf][i2] * scl);
                }
            }
    } else {
#pragma unroll
        for (int mf = 0; mf < 4; mf++)
#pragma unroll
            for (int nf = 0; nf < 2; nf++) {
                int n = col0 + nf * 16;
                int m = row0 + mf * 16;
                int b = m >> 11, s = m & 2047;
                int h = n >> 6, d = n & 63;
                bf16x4 pack = { (bf16)acc[mf][nf][0], (bf16)acc[mf][nf][1],
                                (bf16)acc[mf][nf][2], (bf16)acc[mf][nf][3] };
                *(bf16x4*)(Vt + ((size_t)(b * NUM_HEADS + h) * HEAD_DIM + d) * SEQ + s) = pack;
            }
    }
}

__global__ __launch_bounds__(256) void gemm_outp(const bf16* __restrict__ at,
                                                 const bf16* __restrict__ woT,
                                                 float* __restrict__ out) {
    __shared__ __attribute__((aligned(16))) bf16 As[BM * BK];
    __shared__ __attribute__((aligned(16))) bf16 Bs[BN * BK];
    int m0 = blockIdx.y * BM, n0 = blockIdx.x * BN;
    f32x4 acc[4][2];
    gemm_core(at, woT, m0, n0, DMODEL, As, Bs, acc);

    int lane = threadIdx.x & 63, wave = threadIdx.x >> 6;
    int wm = (wave >> 1) * 64, wn = (wave & 1) * 32;
    int col0 = n0 + wn + (lane & 15);
    int row0 = m0 + wm + (lane >> 4) * 4;
#pragma unroll
    for (int mf = 0; mf < 4; mf++)
#pragma unroll
        for (int nf = 0; nf < 2; nf++) {
            int n = col0 + nf * 16;
            int mb = row0 + mf * 16;
#pragma unroll
            for (int i2 = 0; i2 < 4; i2++)
                out[(size_t)(mb + i2) * DMODEL + n] = acc[mf][nf][i2];
        }
}

// ---------------- flash attention: R12 version, unchanged (44.3 us proven) ----------------
// grid 512, block 512 (8 waves). Pair {p, 31-p} sequential; 8 waves split KV by
// parity (waves 0-3 even tiles, 4-7 odd); wave&3 = 16-row strip. 17 uniform
// iters/block; 16 waves/CU. 4-deep K/V LDS, one pair staged ahead (disjoint
// buffers), plain __syncthreads. In-block parity merge via f32 overlay.
__global__ __launch_bounds__(512, 4) void attn_kernel(const bf16* __restrict__ Qh, const bf16* __restrict__ Kh,
                                                      const bf16* __restrict__ Vt, bf16* __restrict__ attn) {
    __shared__ __attribute__((aligned(16))) bf16 Kl[4 * 64 * 64];   // 4 x 8KB, swizzled [kv][d]
    __shared__ __attribute__((aligned(16))) bf16 Vl[4 * 64 * 64];   // 4 x 8KB, swizzled [d][kv]
    __shared__ __attribute__((aligned(16))) bf16 Pl[8 * 16 * 64];   // per-wave P, 2KB
    int id = blockIdx.x;
    int xcd = id & 7, slot = id >> 3;        // slot 0..63
    int bh4 = slot >> 4;                     // 4 (b,h) per XCD
    int pairIdx = slot & 15;                 // pair {p, 31-p}
    int hb = xcd * 4 + bh4;
    int b = hb >> 4, h = hb & 15;
    int t = threadIdx.x, lane = t & 63, wave = t >> 6;
    int l15 = lane & 15, lg = lane >> 4;
    int strip = wave & 3;                    // 16-row strip within 64-row q-tile
    int gp = wave >> 2;                      // kv parity group (0=even,1=odd)

    const bf16* Qb = Qh + ((size_t)(b * NUM_HEADS + h) * SEQ) * HEAD_DIM;
    const bf16* Kb = Kh + ((size_t)(b * NUM_HEADS + h) * SEQ) * HEAD_DIM;
    const bf16* Vb = Vt + ((size_t)(b * NUM_HEADS + h) * HEAD_DIM) * SEQ;  // [D][S]

    char* Pw = (char*)Pl + wave * 2048;
    int swz = (l15 & 7) << 4;
    float* M = (float*)Kl;                   // merge overlay (used after drain)

    int sc = t;
    int sL = (sc * 16) ^ (((sc >> 3) & 7) << 4);
    int srow = sc >> 3, scole = (sL & 127) >> 1;

    auto STAGE = [&](int kt) {               // stage K+V tile kt (2 gld16/thread)
        int kv0n = kt * 64;
        int bi = kt & 3;
        gld16(Kb + (size_t)(kv0n + srow) * HEAD_DIM + scole, (char*)Kl + bi * 8192 + sc * 16);
        gld16(Vb + (size_t)srow * SEQ + kv0n + scole,        (char*)Vl + bi * 8192 + sc * 16);
    };

#pragma unroll 1
    for (int seg = 0; seg < 2; seg++) {
        int qt = seg ? (31 - pairIdx) : pairIdx;   // q-tile of 64 rows
        int q0w = qt * 64 + strip * 16;            // this wave's 16 q-rows
        int nkt = qt + 1;                          // kv tiles 0..qt
        int imax = (nkt + 1) >> 1;                 // parity-split iterations

        bf16x8 qf[2];
#pragma unroll
        for (int ks = 0; ks < 2; ks++)
            qf[ks] = *(const bf16x8*)(Qb + (size_t)(q0w + l15) * HEAD_DIM + ks * 32 + lg * 8);

        f32x4 oacc[4];
#pragma unroll
        for (int df = 0; df < 4; df++) oacc[df] = (f32x4){0.f, 0.f, 0.f, 0.f};
        float mrun = -1e30f, lrun = 0.f;

        STAGE(0);
        if (nkt > 1) STAGE(1);
        __syncthreads();

#pragma unroll 1
        for (int j = 0; j < imax; j++) {
            int kt = 2 * j + gp;                   // this group's kv tile
            int s0 = 2 * j + 2;                    // ONE pair ahead (disjoint buffers)
            if (s0 < nkt) STAGE(s0);
            if (s0 + 1 < nkt) STAGE(s0 + 1);

            if (kt <= qt) {
                int kv0 = kt * 64;
                const char* KL = (const char*)Kl + (kt & 3) * 8192;
                const char* VL = (const char*)Vl + (kt & 3) * 8192;
                f32x4 st[4];
                __builtin_amdgcn_s_setprio(1);
#pragma unroll
                for (int cf = 0; cf < 4; cf++) {
                    bf16x8 kfr[2];
#pragma unroll
                    for (int ks = 0; ks < 2; ks++) {
                        int off = ((cf * 16 + l15) * 128 + ks * 64 + lg * 16) ^ swz;
                        kfr[ks] = *(const bf16x8*)(KL + off);
                    }
                    st[cf] = (f32x4){0.f, 0.f, 0.f, 0.f};
#pragma unroll
                    for (int ks = 0; ks < 2; ks++)
                        st[cf] = MFMA16(kfr[ks], qf[ks], st[cf]);
                }
                __builtin_amdgcn_s_setprio(0);
                if (kt == qt) {
                    int qrow = q0w + l15;
#pragma unroll
                    for (int cf = 0; cf < 4; cf++)
#pragma unroll
                        for (int i = 0; i < 4; i++) {
                            int kv = kv0 + cf * 16 + lg * 4 + i;
                            if (kv > qrow) st[cf][i] = -1e30f;
                        }
                }
                float m01 = fmaxf(fmaxf(st[0][0], st[0][1]), fmaxf(st[0][2], st[0][3]));
                float m23 = fmaxf(fmaxf(st[1][0], st[1][1]), fmaxf(st[1][2], st[1][3]));
                float m45 = fmaxf(fmaxf(st[2][0], st[2][1]), fmaxf(st[2][2], st[2][3]));
                float m67 = fmaxf(fmaxf(st[3][0], st[3][1]), fmaxf(st[3][2], st[3][3]));
                float mx = fmaxf(fmaxf(m01, m23), fmaxf(m45, m67));
                mx = fmaxf(mx, __shfl_xor(mx, 16, 64));
                mx = fmaxf(mx, __shfl_xor(mx, 32, 64));
                if (!__all(mx <= mrun + 8.0f)) {
                    float mnew = fmaxf(mrun, mx);
                    float alpha = fast_exp2(mrun - mnew);
                    float av[4];
#pragma unroll
                    for (int i = 0; i < 4; i++) av[i] = __shfl(alpha, lg * 4 + i, 64);
#pragma unroll
                    for (int df = 0; df < 4; df++)
#pragma unroll
                        for (int i = 0; i < 4; i++) oacc[df][i] *= av[i];
                    lrun *= alpha;
                    mrun = mnew;
                }
                float psc[4];
                bf16x4 pb[4];
#pragma unroll
                for (int cf = 0; cf < 4; cf++) {
                    float p0 = fast_exp2(st[cf][0] - mrun);
                    float p1 = fast_exp2(st[cf][1] - mrun);
                    float p2 = fast_exp2(st[cf][2] - mrun);
                    float p3 = fast_exp2(st[cf][3] - mrun);
                    psc[cf] = (p0 + p1) + (p2 + p3);
                    pb[cf][0] = (bf16)p0; pb[cf][1] = (bf16)p1;
                    pb[cf][2] = (bf16)p2; pb[cf][3] = (bf16)p3;
                }
                float ps = (psc[0] + psc[1]) + (psc[2] + psc[3]);
                ps += __shfl_xor(ps, 16, 64);
                ps += __shfl_xor(ps, 32, 64);
                lrun += ps;
#pragma unroll
                for (int cf = 0; cf < 4; cf++) {
                    int off = (l15 * 128 + cf * 32 + lg * 8) ^ swz;
                    *(bf16x4*)(Pw + off) = pb[cf];
                }
                bf16x8 pa[2];
#pragma unroll
                for (int ks = 0; ks < 2; ks++) {
                    int off = (l15 * 128 + ks * 64 + lg * 16) ^ swz;
                    pa[ks] = *(const bf16x8*)(Pw + off);
                }
                __builtin_amdgcn_s_setprio(1);
#pragma unroll
                for (int ks = 0; ks < 2; ks++)
#pragma unroll
                    for (int df = 0; df < 4; df++) {
                        int off = ((df * 16 + l15) * 128 + ks * 64 + lg * 16) ^ swz;
                        bf16x8 bv = *(const bf16x8*)(VL + off);
                        oacc[df] = MFMA16(pa[ks], bv, oacc[df]);
                    }
                __builtin_amdgcn_s_setprio(0);
            }
            __syncthreads();
        }

        // ---- in-block merge of the two parity partials (per 16-row strip) ----
        if (gp == 0) {
#pragma unroll
            for (int df = 0; df < 4; df++)
#pragma unroll
                for (int i = 0; i < 4; i++)
                    M[strip * 1040 + (lg * 4 + i) * 65 + df * 16 + l15] = oacc[df][i];
            if (lg == 0) {
                M[4160 + strip * 16 + l15] = mrun;
                M[4224 + strip * 16 + l15] = lrun;
            }
        }
        __syncthreads();
        if (gp == 1) {
            float mA = M[4160 + strip * 16 + l15];
            float lA = M[4224 + strip * 16 + l15];
            float ms = fmaxf(mrun, mA);
            float aB = fast_exp2(mrun - ms);
            float aA = fast_exp2(mA - ms);
            float lrec = 1.0f / (lrun * aB + lA * aA);
            if (lg == 0) {
                M[4288 + strip * 16 + l15] = aA * lrec;
                M[4352 + strip * 16 + l15] = aB * lrec;
            }
        }
        __syncthreads();
        if (gp == 1) {
#pragma unroll
            for (int df = 0; df < 4; df++)
#pragma unroll
                for (int i = 0; i < 4; i++) {
                    int r = lg * 4 + i;
                    float cA = M[4288 + strip * 16 + r];
                    float cB = M[4352 + strip * 16 + r];
                    float oA = M[strip * 1040 + r * 65 + df * 16 + l15];
                    int qrow = qt * 64 + strip * 16 + r;
                    int d = df * 16 + l15;
                    attn[((size_t)(b * SEQ + qrow)) * DMODEL + h * HEAD_DIM + d] =
                        (bf16)(oacc[df][i] * cB + oA * cA);
                }
        }
        __syncthreads();
    }
}

// ---------------- launch ----------------

extern "C" void kernel_launch(void* const* d_in, const int* in_sizes, int n_in,
                              void* d_out, int out_size, void* d_ws, size_t ws_size,
                              hipStream_t stream) {
    const float* x  = (const float*)d_in[0];
    const float* wq = (const float*)d_in[1];
    const float* wk = (const float*)d_in[2];
    const float* wv = (const float*)d_in[3];
    const float* wo = (const float*)d_in[4];
    float* out = (float*)d_out;

    char* w = (char*)d_ws;
    bf16* xb  = (bf16*)(w);                        // 8 MB
    bf16* wqT = (bf16*)(w + (8ull  << 20));        // 2 MB
    bf16* wkT = (bf16*)(w + (10ull << 20));
    bf16* wvT = (bf16*)(w + (12ull << 20));
    bf16* woT = (bf16*)(w + (14ull << 20));
    bf16* Qh  = (bf16*)(w + (16ull << 20));        // 8 MB, [B][H][S][D]
    bf16* Kh  = (bf16*)(w + (24ull << 20));        // 8 MB, [B][H][S][D]
    bf16* Vt  = (bf16*)(w + (32ull << 20));        // 8 MB, [B][H][D][S]
    bf16* at  = (bf16*)(w + (40ull << 20));        // 8 MB  (total 48 MB)

    cvt_all<<<5120, 256, 0, stream>>>(x, wq, wk, wv, wo, xb, wqT, wkT, wvT, woT);
    gemm_qkv<<<dim3(DMODEL / BN, MROWS / BM, 3), 256, 0, stream>>>(xb, wqT, wkT, wvT, Qh, Kh, Vt);
    attn_kernel<<<dim3(512, 1, 1), 512, 0, stream>>>(Qh, Kh, Vt, at);
    gemm_outp<<<dim3(DMODEL / BN, MROWS / BM), 256, 0, stream>>>(at, woT, out);
}

// Round 16
// 109.315 us; speedup vs baseline: 1.1058x; 1.1058x over previous
//
#include <hip/hip_runtime.h>
#include <hip/hip_bf16.h>

#define NUM_HEADS 16
#define HEAD_DIM 64
#define DMODEL 1024
#define SEQ 2048
#define BATCH 2
#define MROWS (BATCH*SEQ)

typedef __bf16 bf16;
typedef __bf16 bf16x4 __attribute__((ext_vector_type(4)));
typedef __bf16 bf16x8 __attribute__((ext_vector_type(8)));
typedef float f32x4 __attribute__((ext_vector_type(4)));

#define MFMA16(a, b, c) __builtin_amdgcn_mfma_f32_16x16x32_bf16((a), (b), (c), 0, 0, 0)

// 0.125 * log2(e): folded into Q so QK^T logits land in exp2 domain
#define QSCALE 0.1803368801111444f

__device__ __forceinline__ float fast_exp2(float x) {
    float r;
    asm("v_exp_f32 %0, %1" : "=v"(r) : "v"(x));
    return r;
}

__device__ __forceinline__ void gld16(const void* g, void* l) {
    __builtin_amdgcn_global_load_lds(
        (const __attribute__((address_space(1))) void*)g,
        (__attribute__((address_space(3))) void*)l, 16, 0, 0);
}

// ---------------- merged conversion kernel (single launch) ----------------
// blocks 0..4095: x f32 -> bf16 (vectorized). blocks 4096..5119: the four
// weight transposes (w [k][n] f32 -> wT [n][k] bf16) via 64x64 LDS tiles.
__global__ __launch_bounds__(256) void cvt_all(const float* __restrict__ x,
                                               const float* __restrict__ w0, const float* __restrict__ w1,
                                               const float* __restrict__ w2, const float* __restrict__ w3,
                                               bf16* __restrict__ xb,
                                               bf16* __restrict__ o0, bf16* __restrict__ o1,
                                               bf16* __restrict__ o2, bf16* __restrict__ o3) {
    __shared__ bf16 tile[64][65];
    int id = blockIdx.x;
    if (id < 4096) {
        int i = id * 256 + threadIdx.x;          // i < 1048576 = MROWS*DMODEL/4
        float4 v = *(const float4*)(x + (size_t)i * 4);
        bf16x4 o = { (bf16)v.x, (bf16)v.y, (bf16)v.z, (bf16)v.w };
        *(bf16x4*)(xb + (size_t)i * 4) = o;
        return;
    }
    id -= 4096;
    int z = id >> 8, r = id & 255;
    int by = r >> 4, bx = r & 15;
    const float* w = z == 0 ? w0 : z == 1 ? w1 : z == 2 ? w2 : w3;
    bf16* o = z == 0 ? o0 : z == 1 ? o1 : z == 2 ? o2 : o3;
    int k0 = by * 64, n0 = bx * 64;
    int tc = threadIdx.x & 63;
    int tr0 = threadIdx.x >> 6;
#pragma unroll
    for (int i = 0; i < 16; i++) {
        int rr = tr0 + i * 4;
        tile[rr][tc] = (bf16)w[(size_t)(k0 + rr) * DMODEL + n0 + tc];
    }
    __syncthreads();
#pragma unroll
    for (int i = 0; i < 16; i++) {
        int rr = tr0 + i * 4;
        o[(size_t)(n0 + rr) * DMODEL + k0 + tc] = tile[tc][rr];
    }
}

// ---------------- GEMM core: C[128][128] tile = A[m][k] * Bt[n][k]^T ----------------
// R12/R14-proven structure (best measured): BK=32, 128x128 tile, single buffer,
// 2 barriers per K-step, linear LDS, compiler-scheduled.
// FALSIFIED alternatives on this workload — do not re-apply:
//  R9  triple-buffer + counted-vmcnt + sched_barrier: 2x slower (m132/m141).
//  R13 BK=64 + XOR swizzle: conflicts->0 but slower (T2 regime-gate: 2-phase
//      critical path is the stage drain, not LDS reads).
//  R15 BN=64: occupancy 14->36% but FETCH 33->60MB (arith intensity halved,
//      L2 overflow) -> slower. Bandwidth was the scarcer resource.

#define BM 128
#define BN 128
#define BK 32

__device__ __forceinline__ void gemm_core(const bf16* __restrict__ A, const bf16* __restrict__ Bt,
                                          int m0, int n0, int Kdim,
                                          bf16* As, bf16* Bs, f32x4 acc[4][4]) {
    int t = threadIdx.x;
    int lane = t & 63;
    int wave = t >> 6;
    int wm = (wave >> 1) * 64;
    int wn = (wave & 1) * 64;
#pragma unroll
    for (int mf = 0; mf < 4; mf++)
#pragma unroll
        for (int nf = 0; nf < 4; nf++) acc[mf][nf] = (f32x4){0.f, 0.f, 0.f, 0.f};

    int arow = lane & 15, kg = lane >> 4;

    for (int k0 = 0; k0 < Kdim; k0 += BK) {
        __syncthreads();
#pragma unroll
        for (int it = 0; it < 2; it++) {
            int chunk = it * 256 + t;
            int rr = chunk >> 2, cc = chunk & 3;
            gld16(A + (size_t)(m0 + rr) * Kdim + k0 + cc * 8, As + chunk * 8);
            gld16(Bt + (size_t)(n0 + rr) * Kdim + k0 + cc * 8, Bs + chunk * 8);
        }
        __syncthreads();
        bf16x8 af[4], bfr[4];
#pragma unroll
        for (int mf = 0; mf < 4; mf++)
            af[mf] = *(const bf16x8*)(As + (wm + mf * 16 + arow) * BK + kg * 8);
#pragma unroll
        for (int nf = 0; nf < 4; nf++)
            bfr[nf] = *(const bf16x8*)(Bs + (wn + nf * 16 + arow) * BK + kg * 8);
#pragma unroll
        for (int mf = 0; mf < 4; mf++)
#pragma unroll
            for (int nf = 0; nf < 4; nf++)
                acc[mf][nf] = MFMA16(af[mf], bfr[nf], acc[mf][nf]);
    }
}

// z=0 -> Q head-major [B][H][S][D], pre-scaled by QSCALE; z=1 -> K head-major; z=2 -> V [B][H][D][S]
// grid (8,32,3) flattens x-fastest/z-slowest: CU c gets the same (bx,by) tile for
// all three z -> A-panel shared in L2 across the QKV triple (natural locality).
__global__ __launch_bounds__(256) void gemm_qkv(const bf16* __restrict__ xb,
                                                const bf16* __restrict__ wqT, const bf16* __restrict__ wkT,
                                                const bf16* __restrict__ wvT,
                                                bf16* __restrict__ Qh, bf16* __restrict__ Kh,
                                                bf16* __restrict__ Vt) {
    __shared__ __attribute__((aligned(16))) bf16 As[BM * BK];
    __shared__ __attribute__((aligned(16))) bf16 Bs[BN * BK];
    int z = blockIdx.z;
    const bf16* Bt = z == 0 ? wqT : z == 1 ? wkT : wvT;
    int m0 = blockIdx.y * BM, n0 = blockIdx.x * BN;
    f32x4 acc[4][4];
    gemm_core(xb, Bt, m0, n0, DMODEL, As, Bs, acc);

    int lane = threadIdx.x & 63, wave = threadIdx.x >> 6;
    int wm = (wave >> 1) * 64, wn = (wave & 1) * 64;
    int col0 = n0 + wn + (lane & 15);
    int row0 = m0 + wm + (lane >> 4) * 4;
    if (z < 2) {
        bf16* O = z == 0 ? Qh : Kh;
        float scl = z == 0 ? QSCALE : 1.0f;
#pragma unroll
        for (int mf = 0; mf < 4; mf++)
#pragma unroll
            for (int nf = 0; nf < 4; nf++) {
                int n = col0 + nf * 16;
                int mb = row0 + mf * 16;
                int hh = n >> 6, d = n & 63;
#pragma unroll
                for (int i2 = 0; i2 < 4; i2++) {
                    int m = mb + i2;
                    int bb = m >> 11, s = m & 2047;
                    O[(((size_t)bb * NUM_HEADS + hh) * SEQ + s) * HEAD_DIM + d] =
                        (bf16)(acc[mf][nf][i2] * scl);
                }
            }
    } else {
#pragma unroll
        for (int mf = 0; mf < 4; mf++)
#pragma unroll
            for (int nf = 0; nf < 4; nf++) {
                int n = col0 + nf * 16;
                int m = row0 + mf * 16;
                int b = m >> 11, s = m & 2047;
                int h = n >> 6, d = n & 63;
                bf16x4 pack = { (bf16)acc[mf][nf][0], (bf16)acc[mf][nf][1],
                                (bf16)acc[mf][nf][2], (bf16)acc[mf][nf][3] };
                *(bf16x4*)(Vt + ((size_t)(b * NUM_HEADS + h) * HEAD_DIM + d) * SEQ + s) = pack;
            }
    }
}

__global__ __launch_bounds__(256) void gemm_outp(const bf16* __restrict__ at,
                                                 const bf16* __restrict__ woT,
                                                 float* __restrict__ out) {
    __shared__ __attribute__((aligned(16))) bf16 As[BM * BK];
    __shared__ __attribute__((aligned(16))) bf16 Bs[BN * BK];
    int m0 = blockIdx.y * BM, n0 = blockIdx.x * BN;
    f32x4 acc[4][4];
    gemm_core(at, woT, m0, n0, DMODEL, As, Bs, acc);

    int lane = threadIdx.x & 63, wave = threadIdx.x >> 6;
    int wm = (wave >> 1) * 64, wn = (wave & 1) * 64;
    int col0 = n0 + wn + (lane & 15);
    int row0 = m0 + wm + (lane >> 4) * 4;
#pragma unroll
    for (int mf = 0; mf < 4; mf++)
#pragma unroll
        for (int nf = 0; nf < 4; nf++) {
            int n = col0 + nf * 16;
            int mb = row0 + mf * 16;
#pragma unroll
            for (int i2 = 0; i2 < 4; i2++)
                out[(size_t)(mb + i2) * DMODEL + n] = acc[mf][nf][i2];
        }
}

// ---------------- flash attention: R12 version, unchanged (44.3 us proven) ----------------
// grid 512, block 512 (8 waves). Pair {p, 31-p} sequential; 8 waves split KV by
// parity (waves 0-3 even tiles, 4-7 odd); wave&3 = 16-row strip. 17 uniform
// iters/block; 16 waves/CU. 4-deep K/V LDS, one pair staged ahead (disjoint
// buffers), plain __syncthreads. In-block parity merge via f32 overlay.
__global__ __launch_bounds__(512, 4) void attn_kernel(const bf16* __restrict__ Qh, const bf16* __restrict__ Kh,
                                                      const bf16* __restrict__ Vt, bf16* __restrict__ attn) {
    __shared__ __attribute__((aligned(16))) bf16 Kl[4 * 64 * 64];   // 4 x 8KB, swizzled [kv][d]
    __shared__ __attribute__((aligned(16))) bf16 Vl[4 * 64 * 64];   // 4 x 8KB, swizzled [d][kv]
    __shared__ __attribute__((aligned(16))) bf16 Pl[8 * 16 * 64];   // per-wave P, 2KB
    int id = blockIdx.x;
    int xcd = id & 7, slot = id >> 3;        // slot 0..63
    int bh4 = slot >> 4;                     // 4 (b,h) per XCD
    int pairIdx = slot & 15;                 // pair {p, 31-p}
    int hb = xcd * 4 + bh4;
    int b = hb >> 4, h = hb & 15;
    int t = threadIdx.x, lane = t & 63, wave = t >> 6;
    int l15 = lane & 15, lg = lane >> 4;
    int strip = wave & 3;                    // 16-row strip within 64-row q-tile
    int gp = wave >> 2;                      // kv parity group (0=even,1=odd)

    const bf16* Qb = Qh + ((size_t)(b * NUM_HEADS + h) * SEQ) * HEAD_DIM;
    const bf16* Kb = Kh + ((size_t)(b * NUM_HEADS + h) * SEQ) * HEAD_DIM;
    const bf16* Vb = Vt + ((size_t)(b * NUM_HEADS + h) * HEAD_DIM) * SEQ;  // [D][S]

    char* Pw = (char*)Pl + wave * 2048;
    int swz = (l15 & 7) << 4;
    float* M = (float*)Kl;                   // merge overlay (used after drain)

    int sc = t;
    int sL = (sc * 16) ^ (((sc >> 3) & 7) << 4);
    int srow = sc >> 3, scole = (sL & 127) >> 1;

    auto STAGE = [&](int kt) {               // stage K+V tile kt (2 gld16/thread)
        int kv0n = kt * 64;
        int bi = kt & 3;
        gld16(Kb + (size_t)(kv0n + srow) * HEAD_DIM + scole, (char*)Kl + bi * 8192 + sc * 16);
        gld16(Vb + (size_t)srow * SEQ + kv0n + scole,        (char*)Vl + bi * 8192 + sc * 16);
    };

#pragma unroll 1
    for (int seg = 0; seg < 2; seg++) {
        int qt = seg ? (31 - pairIdx) : pairIdx;   // q-tile of 64 rows
        int q0w = qt * 64 + strip * 16;            // this wave's 16 q-rows
        int nkt = qt + 1;                          // kv tiles 0..qt
        int imax = (nkt + 1) >> 1;                 // parity-split iterations

        bf16x8 qf[2];
#pragma unroll
        for (int ks = 0; ks < 2; ks++)
            qf[ks] = *(const bf16x8*)(Qb + (size_t)(q0w + l15) * HEAD_DIM + ks * 32 + lg * 8);

        f32x4 oacc[4];
#pragma unroll
        for (int df = 0; df < 4; df++) oacc[df] = (f32x4){0.f, 0.f, 0.f, 0.f};
        float mrun = -1e30f, lrun = 0.f;

        STAGE(0);
        if (nkt > 1) STAGE(1);
        __syncthreads();

#pragma unroll 1
        for (int j = 0; j < imax; j++) {
            int kt = 2 * j + gp;                   // this group's kv tile
            int s0 = 2 * j + 2;                    // ONE pair ahead (disjoint buffers)
            if (s0 < nkt) STAGE(s0);
            if (s0 + 1 < nkt) STAGE(s0 + 1);

            if (kt <= qt) {
                int kv0 = kt * 64;
                const char* KL = (const char*)Kl + (kt & 3) * 8192;
                const char* VL = (const char*)Vl + (kt & 3) * 8192;
                f32x4 st[4];
                __builtin_amdgcn_s_setprio(1);
#pragma unroll
                for (int cf = 0; cf < 4; cf++) {
                    bf16x8 kfr[2];
#pragma unroll
                    for (int ks = 0; ks < 2; ks++) {
                        int off = ((cf * 16 + l15) * 128 + ks * 64 + lg * 16) ^ swz;
                        kfr[ks] = *(const bf16x8*)(KL + off);
                    }
                    st[cf] = (f32x4){0.f, 0.f, 0.f, 0.f};
#pragma unroll
                    for (int ks = 0; ks < 2; ks++)
                        st[cf] = MFMA16(kfr[ks], qf[ks], st[cf]);
                }
                __builtin_amdgcn_s_setprio(0);
                if (kt == qt) {
                    int qrow = q0w + l15;
#pragma unroll
                    for (int cf = 0; cf < 4; cf++)
#pragma unroll
                        for (int i = 0; i < 4; i++) {
                            int kv = kv0 + cf * 16 + lg * 4 + i;
                            if (kv > qrow) st[cf][i] = -1e30f;
                        }
                }
                float m01 = fmaxf(fmaxf(st[0][0], st[0][1]), fmaxf(st[0][2], st[0][3]));
                float m23 = fmaxf(fmaxf(st[1][0], st[1][1]), fmaxf(st[1][2], st[1][3]));
                float m45 = fmaxf(fmaxf(st[2][0], st[2][1]), fmaxf(st[2][2], st[2][3]));
                float m67 = fmaxf(fmaxf(st[3][0], st[3][1]), fmaxf(st[3][2], st[3][3]));
                float mx = fmaxf(fmaxf(m01, m23), fmaxf(m45, m67));
                mx = fmaxf(mx, __shfl_xor(mx, 16, 64));
                mx = fmaxf(mx, __shfl_xor(mx, 32, 64));
                if (!__all(mx <= mrun + 8.0f)) {
                    float mnew = fmaxf(mrun, mx);
                    float alpha = fast_exp2(mrun - mnew);
                    float av[4];
#pragma unroll
                    for (int i = 0; i < 4; i++) av[i] = __shfl(alpha, lg * 4 + i, 64);
#pragma unroll
                    for (int df = 0; df < 4; df++)
#pragma unroll
                        for (int i = 0; i < 4; i++) oacc[df][i] *= av[i];
                    lrun *= alpha;
                    mrun = mnew;
                }
                float psc[4];
                bf16x4 pb[4];
#pragma unroll
                for (int cf = 0; cf < 4; cf++) {
                    float p0 = fast_exp2(st[cf][0] - mrun);
                    float p1 = fast_exp2(st[cf][1] - mrun);
                    float p2 = fast_exp2(st[cf][2] - mrun);
                    float p3 = fast_exp2(st[cf][3] - mrun);
                    psc[cf] = (p0 + p1) + (p2 + p3);
                    pb[cf][0] = (bf16)p0; pb[cf][1] = (bf16)p1;
                    pb[cf][2] = (bf16)p2; pb[cf][3] = (bf16)p3;
                }
                float ps = (psc[0] + psc[1]) + (psc[2] + psc[3]);
                ps += __shfl_xor(ps, 16, 64);
                ps += __shfl_xor(ps, 32, 64);
                lrun += ps;
#pragma unroll
                for (int cf = 0; cf < 4; cf++) {
                    int off = (l15 * 128 + cf * 32 + lg * 8) ^ swz;
                    *(bf16x4*)(Pw + off) = pb[cf];
                }
                bf16x8 pa[2];
#pragma unroll
                for (int ks = 0; ks < 2; ks++) {
                    int off = (l15 * 128 + ks * 64 + lg * 16) ^ swz;
                    pa[ks] = *(const bf16x8*)(Pw + off);
                }
                __builtin_amdgcn_s_setprio(1);
#pragma unroll
                for (int ks = 0; ks < 2; ks++)
#pragma unroll
                    for (int df = 0; df < 4; df++) {
                        int off = ((df * 16 + l15) * 128 + ks * 64 + lg * 16) ^ swz;
                        bf16x8 bv = *(const bf16x8*)(VL + off);
                        oacc[df] = MFMA16(pa[ks], bv, oacc[df]);
                    }
                __builtin_amdgcn_s_setprio(0);
            }
            __syncthreads();
        }

        // ---- in-block merge of the two parity partials (per 16-row strip) ----
        if (gp == 0) {
#pragma unroll
            for (int df = 0; df < 4; df++)
#pragma unroll
                for (int i = 0; i < 4; i++)
                    M[strip * 1040 + (lg * 4 + i) * 65 + df * 16 + l15] = oacc[df][i];
            if (lg == 0) {
                M[4160 + strip * 16 + l15] = mrun;
                M[4224 + strip * 16 + l15] = lrun;
            }
        }
        __syncthreads();
        if (gp == 1) {
            float mA = M[4160 + strip * 16 + l15];
            float lA = M[4224 + strip * 16 + l15];
            float ms = fmaxf(mrun, mA);
            float aB = fast_exp2(mrun - ms);
            float aA = fast_exp2(mA - ms);
            float lrec = 1.0f / (lrun * aB + lA * aA);
            if (lg == 0) {
                M[4288 + strip * 16 + l15] = aA * lrec;
                M[4352 + strip * 16 + l15] = aB * lrec;
            }
        }
        __syncthreads();
        if (gp == 1) {
#pragma unroll
            for (int df = 0; df < 4; df++)
#pragma unroll
                for (int i = 0; i < 4; i++) {
                    int r = lg * 4 + i;
                    float cA = M[4288 + strip * 16 + r];
                    float cB = M[4352 + strip * 16 + r];
                    float oA = M[strip * 1040 + r * 65 + df * 16 + l15];
                    int qrow = qt * 64 + strip * 16 + r;
                    int d = df * 16 + l15;
                    attn[((size_t)(b * SEQ + qrow)) * DMODEL + h * HEAD_DIM + d] =
                        (bf16)(oacc[df][i] * cB + oA * cA);
                }
        }
        __syncthreads();
    }
}

// ---------------- launch ----------------

extern "C" void kernel_launch(void* const* d_in, const int* in_sizes, int n_in,
                              void* d_out, int out_size, void* d_ws, size_t ws_size,
                              hipStream_t stream) {
    const float* x  = (const float*)d_in[0];
    const float* wq = (const float*)d_in[1];
    const float* wk = (const float*)d_in[2];
    const float* wv = (const float*)d_in[3];
    const float* wo = (const float*)d_in[4];
    float* out = (float*)d_out;

    char* w = (char*)d_ws;
    bf16* xb  = (bf16*)(w);                        // 8 MB
    bf16* wqT = (bf16*)(w + (8ull  << 20));        // 2 MB
    bf16* wkT = (bf16*)(w + (10ull << 20));
    bf16* wvT = (bf16*)(w + (12ull << 20));
    bf16* woT = (bf16*)(w + (14ull << 20));
    bf16* Qh  = (bf16*)(w + (16ull << 20));        // 8 MB, [B][H][S][D]
    bf16* Kh  = (bf16*)(w + (24ull << 20));        // 8 MB, [B][H][S][D]
    bf16* Vt  = (bf16*)(w + (32ull << 20));        // 8 MB, [B][H][D][S]
    bf16* at  = (bf16*)(w + (40ull << 20));        // 8 MB  (total 48 MB)

    cvt_all<<<5120, 256, 0, stream>>>(x, wq, wk, wv, wo, xb, wqT, wkT, wvT, woT);
    gemm_qkv<<<dim3(DMODEL / BN, MROWS / BM, 3), 256, 0, stream>>>(xb, wqT, wkT, wvT, Qh, Kh, Vt);
    attn_kernel<<<dim3(512, 1, 1), 512, 0, stream>>>(Qh, Kh, Vt, at);
    gemm_outp<<<dim3(DMODEL / BN, MROWS / BM), 256, 0, stream>>>(at, woT, out);
}

// Round 17
// 108.629 us; speedup vs baseline: 1.1128x; 1.0063x over previous
//
#include <hip/hip_runtime.h>
#include <hip/hip_bf16.h>

#define NUM_HEADS 16
#define HEAD_DIM 64
#define DMODEL 1024
#define SEQ 2048
#define BATCH 2
#define MROWS (BATCH*SEQ)

typedef __bf16 bf16;
typedef __bf16 bf16x4 __attribute__((ext_vector_type(4)));
typedef __bf16 bf16x8 __attribute__((ext_vector_type(8)));
typedef float f32x4 __attribute__((ext_vector_type(4)));

#define MFMA16(a, b, c) __builtin_amdgcn_mfma_f32_16x16x32_bf16((a), (b), (c), 0, 0, 0)

// 0.125 * log2(e): folded into Q so QK^T logits land in exp2 domain
#define QSCALE 0.1803368801111444f

__device__ __forceinline__ float fast_exp2(float x) {
    float r;
    asm("v_exp_f32 %0, %1" : "=v"(r) : "v"(x));
    return r;
}

__device__ __forceinline__ void gld16(const void* g, void* l) {
    __builtin_amdgcn_global_load_lds(
        (const __attribute__((address_space(1))) void*)g,
        (__attribute__((address_space(3))) void*)l, 16, 0, 0);
}

// ---------------- merged conversion kernel (single launch) ----------------
__global__ __launch_bounds__(256) void cvt_all(const float* __restrict__ x,
                                               const float* __restrict__ w0, const float* __restrict__ w1,
                                               const float* __restrict__ w2, const float* __restrict__ w3,
                                               bf16* __restrict__ xb,
                                               bf16* __restrict__ o0, bf16* __restrict__ o1,
                                               bf16* __restrict__ o2, bf16* __restrict__ o3) {
    __shared__ bf16 tile[64][65];
    int id = blockIdx.x;
    if (id < 4096) {
        int i = id * 256 + threadIdx.x;          // i < 1048576 = MROWS*DMODEL/4
        float4 v = *(const float4*)(x + (size_t)i * 4);
        bf16x4 o = { (bf16)v.x, (bf16)v.y, (bf16)v.z, (bf16)v.w };
        *(bf16x4*)(xb + (size_t)i * 4) = o;
        return;
    }
    id -= 4096;
    int z = id >> 8, r = id & 255;
    int by = r >> 4, bx = r & 15;
    const float* w = z == 0 ? w0 : z == 1 ? w1 : z == 2 ? w2 : w3;
    bf16* o = z == 0 ? o0 : z == 1 ? o1 : z == 2 ? o2 : o3;
    int k0 = by * 64, n0 = bx * 64;
    int tc = threadIdx.x & 63;
    int tr0 = threadIdx.x >> 6;
#pragma unroll
    for (int i = 0; i < 16; i++) {
        int rr = tr0 + i * 4;
        tile[rr][tc] = (bf16)w[(size_t)(k0 + rr) * DMODEL + n0 + tc];
    }
    __syncthreads();
#pragma unroll
    for (int i = 0; i < 16; i++) {
        int rr = tr0 + i * 4;
        o[(size_t)(n0 + rr) * DMODEL + k0 + tc] = tile[tc][rr];
    }
}

// ---------------- GEMM core: C[128][128] tile = A[m][k] * Bt[n][k]^T ----------------
// R12/R14-proven structure (best measured): BK=32, 128x128 tile, single buffer,
// 2 barriers per K-step, linear LDS, compiler-scheduled.
// FALSIFIED alternatives on this workload — do not re-apply:
//  R9  triple-buffer + counted-vmcnt + sched_barrier: 2x slower (m132/m141).
//  R13 BK=64 + XOR swizzle: conflicts->0 but slower (stage-drain critical path).
//  R15 BN=64: occupancy up but FETCH 33->60MB (arith intensity halved) -> slower.
// THIS round adds ONLY the XCD tile remap (T1), isolated from R13's confounds:
// R13's FETCH was 32.8MB vs 58-68MB for every natural-mapping variant — the
// remap was the traffic cut. Pure index permutation; core untouched.

#define BM 128
#define BN 128
#define BK 32

__device__ __forceinline__ void gemm_core(const bf16* __restrict__ A, const bf16* __restrict__ Bt,
                                          int m0, int n0, int Kdim,
                                          bf16* As, bf16* Bs, f32x4 acc[4][4]) {
    int t = threadIdx.x;
    int lane = t & 63;
    int wave = t >> 6;
    int wm = (wave >> 1) * 64;
    int wn = (wave & 1) * 64;
#pragma unroll
    for (int mf = 0; mf < 4; mf++)
#pragma unroll
        for (int nf = 0; nf < 4; nf++) acc[mf][nf] = (f32x4){0.f, 0.f, 0.f, 0.f};

    int arow = lane & 15, kg = lane >> 4;

    for (int k0 = 0; k0 < Kdim; k0 += BK) {
        __syncthreads();
#pragma unroll
        for (int it = 0; it < 2; it++) {
            int chunk = it * 256 + t;
            int rr = chunk >> 2, cc = chunk & 3;
            gld16(A + (size_t)(m0 + rr) * Kdim + k0 + cc * 8, As + chunk * 8);
            gld16(Bt + (size_t)(n0 + rr) * Kdim + k0 + cc * 8, Bs + chunk * 8);
        }
        __syncthreads();
        bf16x8 af[4], bfr[4];
#pragma unroll
        for (int mf = 0; mf < 4; mf++)
            af[mf] = *(const bf16x8*)(As + (wm + mf * 16 + arow) * BK + kg * 8);
#pragma unroll
        for (int nf = 0; nf < 4; nf++)
            bfr[nf] = *(const bf16x8*)(Bs + (wn + nf * 16 + arow) * BK + kg * 8);
#pragma unroll
        for (int mf = 0; mf < 4; mf++)
#pragma unroll
            for (int nf = 0; nf < 4; nf++)
                acc[mf][nf] = MFMA16(af[mf], bfr[nf], acc[mf][nf]);
    }
}

// XCD-aware tile remap (T1): f = bx + 8*by in [0,256). xcd = f&7 owns 4
// contiguous M-panels x all 8 N-tiles -> per-XCD working set = A 1MB + B 2MB
// = 3MB, fits the 4MB per-XCD L2 (natural mapping spreads each A-panel across
// all 8 XCDs -> every L2 pulls the whole 8MB A; R9/R15 FETCH 60-68MB vs R13's
// 32.8MB with this remap). Bijective: mtile = xcd*4 + (k&3), ntile = k>>2.
__device__ __forceinline__ void xcd_remap(int bx, int by, int& m0, int& n0) {
    int f = bx + 8 * by;
    int xcd = f & 7, k = f >> 3;
    m0 = (xcd * 4 + (k & 3)) * BM;
    n0 = (k >> 2) * BN;
}

// z=0 -> Q head-major [B][H][S][D], pre-scaled by QSCALE; z=1 -> K head-major; z=2 -> V [B][H][D][S]
__global__ __launch_bounds__(256) void gemm_qkv(const bf16* __restrict__ xb,
                                                const bf16* __restrict__ wqT, const bf16* __restrict__ wkT,
                                                const bf16* __restrict__ wvT,
                                                bf16* __restrict__ Qh, bf16* __restrict__ Kh,
                                                bf16* __restrict__ Vt) {
    __shared__ __attribute__((aligned(16))) bf16 As[BM * BK];
    __shared__ __attribute__((aligned(16))) bf16 Bs[BN * BK];
    int z = blockIdx.z;
    const bf16* Bt = z == 0 ? wqT : z == 1 ? wkT : wvT;
    int m0, n0;
    xcd_remap(blockIdx.x, blockIdx.y, m0, n0);
    f32x4 acc[4][4];
    gemm_core(xb, Bt, m0, n0, DMODEL, As, Bs, acc);

    int lane = threadIdx.x & 63, wave = threadIdx.x >> 6;
    int wm = (wave >> 1) * 64, wn = (wave & 1) * 64;
    int col0 = n0 + wn + (lane & 15);
    int row0 = m0 + wm + (lane >> 4) * 4;
    if (z < 2) {
        bf16* O = z == 0 ? Qh : Kh;
        float scl = z == 0 ? QSCALE : 1.0f;
#pragma unroll
        for (int mf = 0; mf < 4; mf++)
#pragma unroll
            for (int nf = 0; nf < 4; nf++) {
                int n = col0 + nf * 16;
                int mb = row0 + mf * 16;
                int hh = n >> 6, d = n & 63;
#pragma unroll
                for (int i2 = 0; i2 < 4; i2++) {
                    int m = mb + i2;
                    int bb = m >> 11, s = m & 2047;
                    O[(((size_t)bb * NUM_HEADS + hh) * SEQ + s) * HEAD_DIM + d] =
                        (bf16)(acc[mf][nf][i2] * scl);
                }
            }
    } else {
#pragma unroll
        for (int mf = 0; mf < 4; mf++)
#pragma unroll
            for (int nf = 0; nf < 4; nf++) {
                int n = col0 + nf * 16;
                int m = row0 + mf * 16;
                int b = m >> 11, s = m & 2047;
                int h = n >> 6, d = n & 63;
                bf16x4 pack = { (bf16)acc[mf][nf][0], (bf16)acc[mf][nf][1],
                                (bf16)acc[mf][nf][2], (bf16)acc[mf][nf][3] };
                *(bf16x4*)(Vt + ((size_t)(b * NUM_HEADS + h) * HEAD_DIM + d) * SEQ + s) = pack;
            }
    }
}

__global__ __launch_bounds__(256) void gemm_outp(const bf16* __restrict__ at,
                                                 const bf16* __restrict__ woT,
                                                 float* __restrict__ out) {
    __shared__ __attribute__((aligned(16))) bf16 As[BM * BK];
    __shared__ __attribute__((aligned(16))) bf16 Bs[BN * BK];
    int m0, n0;
    xcd_remap(blockIdx.x, blockIdx.y, m0, n0);
    f32x4 acc[4][4];
    gemm_core(at, woT, m0, n0, DMODEL, As, Bs, acc);

    int lane = threadIdx.x & 63, wave = threadIdx.x >> 6;
    int wm = (wave >> 1) * 64, wn = (wave & 1) * 64;
    int col0 = n0 + wn + (lane & 15);
    int row0 = m0 + wm + (lane >> 4) * 4;
#pragma unroll
    for (int mf = 0; mf < 4; mf++)
#pragma unroll
        for (int nf = 0; nf < 4; nf++) {
            int n = col0 + nf * 16;
            int mb = row0 + mf * 16;
#pragma unroll
            for (int i2 = 0; i2 < 4; i2++)
                out[(size_t)(mb + i2) * DMODEL + n] = acc[mf][nf][i2];
        }
}

// ---------------- flash attention: R12 version, unchanged (44 us proven) ----------------
// grid 512, block 512 (8 waves). Pair {p, 31-p} sequential; 8 waves split KV by
// parity (waves 0-3 even tiles, 4-7 odd); wave&3 = 16-row strip. 17 uniform
// iters/block; 16 waves/CU. 4-deep K/V LDS, one pair staged ahead (disjoint
// buffers), plain __syncthreads. In-block parity merge via f32 overlay.
__global__ __launch_bounds__(512, 4) void attn_kernel(const bf16* __restrict__ Qh, const bf16* __restrict__ Kh,
                                                      const bf16* __restrict__ Vt, bf16* __restrict__ attn) {
    __shared__ __attribute__((aligned(16))) bf16 Kl[4 * 64 * 64];   // 4 x 8KB, swizzled [kv][d]
    __shared__ __attribute__((aligned(16))) bf16 Vl[4 * 64 * 64];   // 4 x 8KB, swizzled [d][kv]
    __shared__ __attribute__((aligned(16))) bf16 Pl[8 * 16 * 64];   // per-wave P, 2KB
    int id = blockIdx.x;
    int xcd = id & 7, slot = id >> 3;        // slot 0..63
    int bh4 = slot >> 4;                     // 4 (b,h) per XCD
    int pairIdx = slot & 15;                 // pair {p, 31-p}
    int hb = xcd * 4 + bh4;
    int b = hb >> 4, h = hb & 15;
    int t = threadIdx.x, lane = t & 63, wave = t >> 6;
    int l15 = lane & 15, lg = lane >> 4;
    int strip = wave & 3;                    // 16-row strip within 64-row q-tile
    int gp = wave >> 2;                      // kv parity group (0=even,1=odd)

    const bf16* Qb = Qh + ((size_t)(b * NUM_HEADS + h) * SEQ) * HEAD_DIM;
    const bf16* Kb = Kh + ((size_t)(b * NUM_HEADS + h) * SEQ) * HEAD_DIM;
    const bf16* Vb = Vt + ((size_t)(b * NUM_HEADS + h) * HEAD_DIM) * SEQ;  // [D][S]

    char* Pw = (char*)Pl + wave * 2048;
    int swz = (l15 & 7) << 4;
    float* M = (float*)Kl;                   // merge overlay (used after drain)

    int sc = t;
    int sL = (sc * 16) ^ (((sc >> 3) & 7) << 4);
    int srow = sc >> 3, scole = (sL & 127) >> 1;

    auto STAGE = [&](int kt) {               // stage K+V tile kt (2 gld16/thread)
        int kv0n = kt * 64;
        int bi = kt & 3;
        gld16(Kb + (size_t)(kv0n + srow) * HEAD_DIM + scole, (char*)Kl + bi * 8192 + sc * 16);
        gld16(Vb + (size_t)srow * SEQ + kv0n + scole,        (char*)Vl + bi * 8192 + sc * 16);
    };

#pragma unroll 1
    for (int seg = 0; seg < 2; seg++) {
        int qt = seg ? (31 - pairIdx) : pairIdx;   // q-tile of 64 rows
        int q0w = qt * 64 + strip * 16;            // this wave's 16 q-rows
        int nkt = qt + 1;                          // kv tiles 0..qt
        int imax = (nkt + 1) >> 1;                 // parity-split iterations

        bf16x8 qf[2];
#pragma unroll
        for (int ks = 0; ks < 2; ks++)
            qf[ks] = *(const bf16x8*)(Qb + (size_t)(q0w + l15) * HEAD_DIM + ks * 32 + lg * 8);

        f32x4 oacc[4];
#pragma unroll
        for (int df = 0; df < 4; df++) oacc[df] = (f32x4){0.f, 0.f, 0.f, 0.f};
        float mrun = -1e30f, lrun = 0.f;

        STAGE(0);
        if (nkt > 1) STAGE(1);
        __syncthreads();

#pragma unroll 1
        for (int j = 0; j < imax; j++) {
            int kt = 2 * j + gp;                   // this group's kv tile
            int s0 = 2 * j + 2;                    // ONE pair ahead (disjoint buffers)
            if (s0 < nkt) STAGE(s0);
            if (s0 + 1 < nkt) STAGE(s0 + 1);

            if (kt <= qt) {
                int kv0 = kt * 64;
                const char* KL = (const char*)Kl + (kt & 3) * 8192;
                const char* VL = (const char*)Vl + (kt & 3) * 8192;
                f32x4 st[4];
                __builtin_amdgcn_s_setprio(1);
#pragma unroll
                for (int cf = 0; cf < 4; cf++) {
                    bf16x8 kfr[2];
#pragma unroll
                    for (int ks = 0; ks < 2; ks++) {
                        int off = ((cf * 16 + l15) * 128 + ks * 64 + lg * 16) ^ swz;
                        kfr[ks] = *(const bf16x8*)(KL + off);
                    }
                    st[cf] = (f32x4){0.f, 0.f, 0.f, 0.f};
#pragma unroll
                    for (int ks = 0; ks < 2; ks++)
                        st[cf] = MFMA16(kfr[ks], qf[ks], st[cf]);
                }
                __builtin_amdgcn_s_setprio(0);
                if (kt == qt) {
                    int qrow = q0w + l15;
#pragma unroll
                    for (int cf = 0; cf < 4; cf++)
#pragma unroll
                        for (int i = 0; i < 4; i++) {
                            int kv = kv0 + cf * 16 + lg * 4 + i;
                            if (kv > qrow) st[cf][i] = -1e30f;
                        }
                }
                float m01 = fmaxf(fmaxf(st[0][0], st[0][1]), fmaxf(st[0][2], st[0][3]));
                float m23 = fmaxf(fmaxf(st[1][0], st[1][1]), fmaxf(st[1][2], st[1][3]));
                float m45 = fmaxf(fmaxf(st[2][0], st[2][1]), fmaxf(st[2][2], st[2][3]));
                float m67 = fmaxf(fmaxf(st[3][0], st[3][1]), fmaxf(st[3][2], st[3][3]));
                float mx = fmaxf(fmaxf(m01, m23), fmaxf(m45, m67));
                mx = fmaxf(mx, __shfl_xor(mx, 16, 64));
                mx = fmaxf(mx, __shfl_xor(mx, 32, 64));
                if (!__all(mx <= mrun + 8.0f)) {
                    float mnew = fmaxf(mrun, mx);
                    float alpha = fast_exp2(mrun - mnew);
                    float av[4];
#pragma unroll
                    for (int i = 0; i < 4; i++) av[i] = __shfl(alpha, lg * 4 + i, 64);
#pragma unroll
                    for (int df = 0; df < 4; df++)
#pragma unroll
                        for (int i = 0; i < 4; i++) oacc[df][i] *= av[i];
                    lrun *= alpha;
                    mrun = mnew;
                }
                float psc[4];
                bf16x4 pb[4];
#pragma unroll
                for (int cf = 0; cf < 4; cf++) {
                    float p0 = fast_exp2(st[cf][0] - mrun);
                    float p1 = fast_exp2(st[cf][1] - mrun);
                    float p2 = fast_exp2(st[cf][2] - mrun);
                    float p3 = fast_exp2(st[cf][3] - mrun);
                    psc[cf] = (p0 + p1) + (p2 + p3);
                    pb[cf][0] = (bf16)p0; pb[cf][1] = (bf16)p1;
                    pb[cf][2] = (bf16)p2; pb[cf][3] = (bf16)p3;
                }
                float ps = (psc[0] + psc[1]) + (psc[2] + psc[3]);
                ps += __shfl_xor(ps, 16, 64);
                ps += __shfl_xor(ps, 32, 64);
                lrun += ps;
#pragma unroll
                for (int cf = 0; cf < 4; cf++) {
                    int off = (l15 * 128 + cf * 32 + lg * 8) ^ swz;
                    *(bf16x4*)(Pw + off) = pb[cf];
                }
                bf16x8 pa[2];
#pragma unroll
                for (int ks = 0; ks < 2; ks++) {
                    int off = (l15 * 128 + ks * 64 + lg * 16) ^ swz;
                    pa[ks] = *(const bf16x8*)(Pw + off);
                }
                __builtin_amdgcn_s_setprio(1);
#pragma unroll
                for (int ks = 0; ks < 2; ks++)
#pragma unroll
                    for (int df = 0; df < 4; df++) {
                        int off = ((df * 16 + l15) * 128 + ks * 64 + lg * 16) ^ swz;
                        bf16x8 bv = *(const bf16x8*)(VL + off);
                        oacc[df] = MFMA16(pa[ks], bv, oacc[df]);
                    }
                __builtin_amdgcn_s_setprio(0);
            }
            __syncthreads();
        }

        // ---- in-block merge of the two parity partials (per 16-row strip) ----
        if (gp == 0) {
#pragma unroll
            for (int df = 0; df < 4; df++)
#pragma unroll
                for (int i = 0; i < 4; i++)
                    M[strip * 1040 + (lg * 4 + i) * 65 + df * 16 + l15] = oacc[df][i];
            if (lg == 0) {
                M[4160 + strip * 16 + l15] = mrun;
                M[4224 + strip * 16 + l15] = lrun;
            }
        }
        __syncthreads();
        if (gp == 1) {
            float mA = M[4160 + strip * 16 + l15];
            float lA = M[4224 + strip * 16 + l15];
            float ms = fmaxf(mrun, mA);
            float aB = fast_exp2(mrun - ms);
            float aA = fast_exp2(mA - ms);
            float lrec = 1.0f / (lrun * aB + lA * aA);
            if (lg == 0) {
                M[4288 + strip * 16 + l15] = aA * lrec;
                M[4352 + strip * 16 + l15] = aB * lrec;
            }
        }
        __syncthreads();
        if (gp == 1) {
#pragma unroll
            for (int df = 0; df < 4; df++)
#pragma unroll
                for (int i = 0; i < 4; i++) {
                    int r = lg * 4 + i;
                    float cA = M[4288 + strip * 16 + r];
                    float cB = M[4352 + strip * 16 + r];
                    float oA = M[strip * 1040 + r * 65 + df * 16 + l15];
                    int qrow = qt * 64 + strip * 16 + r;
                    int d = df * 16 + l15;
                    attn[((size_t)(b * SEQ + qrow)) * DMODEL + h * HEAD_DIM + d] =
                        (bf16)(oacc[df][i] * cB + oA * cA);
                }
        }
        __syncthreads();
    }
}

// ---------------- launch ----------------

extern "C" void kernel_launch(void* const* d_in, const int* in_sizes, int n_in,
                              void* d_out, int out_size, void* d_ws, size_t ws_size,
                              hipStream_t stream) {
    const float* x  = (const float*)d_in[0];
    const float* wq = (const float*)d_in[1];
    const float* wk = (const float*)d_in[2];
    const float* wv = (const float*)d_in[3];
    const float* wo = (const float*)d_in[4];
    float* out = (float*)d_out;

    char* w = (char*)d_ws;
    bf16* xb  = (bf16*)(w);                        // 8 MB
    bf16* wqT = (bf16*)(w + (8ull  << 20));        // 2 MB
    bf16* wkT = (bf16*)(w + (10ull << 20));
    bf16* wvT = (bf16*)(w + (12ull << 20));
    bf16* woT = (bf16*)(w + (14ull << 20));
    bf16* Qh  = (bf16*)(w + (16ull << 20));        // 8 MB, [B][H][S][D]
    bf16* Kh  = (bf16*)(w + (24ull << 20));        // 8 MB, [B][H][S][D]
    bf16* Vt  = (bf16*)(w + (32ull << 20));        // 8 MB, [B][H][D][S]
    bf16* at  = (bf16*)(w + (40ull << 20));        // 8 MB  (total 48 MB)

    cvt_all<<<5120, 256, 0, stream>>>(x, wq, wk, wv, wo, xb, wqT, wkT, wvT, woT);
    gemm_qkv<<<dim3(DMODEL / BN, MROWS / BM, 3), 256, 0, stream>>>(xb, wqT, wkT, wvT, Qh, Kh, Vt);
    attn_kernel<<<dim3(512, 1, 1), 512, 0, stream>>>(Qh, Kh, Vt, at);
    gemm_outp<<<dim3(DMODEL / BN, MROWS / BM), 256, 0, stream>>>(at, woT, out);
}